// Round 4
// baseline (21963.881 us; speedup 1.0000x reference)
//
#include <hip/hip_runtime.h>
#include <hip/hip_fp16.h>

typedef _Float16 half8 __attribute__((ext_vector_type(8)));
typedef _Float16 half4_t __attribute__((ext_vector_type(4)));
typedef float    float4_ __attribute__((ext_vector_type(4)));

#define TSTEPS 512
#define NA 64
#define NB 128
#define NC 8

// workspace layout (bytes)
#define FLA_OFF   0               // 64 ints  — layer-1 block flags
#define FLB_OFF   512             // 128 ints — layer-2 block flags
#define FLC_OFF   1536            // 8 ints   — output block flags
#define H1_OFF    4096
#define H1_PHASE  262144          // 1024 cols x 128 batch x 2B, fragment-major
#define H2_OFF    (H1_OFF + 2 * H1_PHASE)
#define X_OFF     (H2_OFF + 2 * H1_PHASE)
#define X_TSTRIDE 16384           // 64 cols x 128 batch x 2B per step
#define ZERO_BYTES X_OFF          // flags + H1 + H2 zeroed each call

__device__ __forceinline__ float sigf(float x) { return 1.0f / (1.0f + __expf(-x)); }

__device__ __forceinline__ half8 zero8() {
    half8 z;
#pragma unroll
    for (int j = 0; j < 8; ++j) z[j] = (_Float16)0.0f;
    return z;
}

__device__ __forceinline__ half8 wfrag_load(const float* Wa, int lda,
                                            const float* Wb, int ldb,
                                            int split, int row, int k0) {
    const float* s = (k0 < split) ? (Wa + (size_t)row * lda + k0)
                                  : (Wb + (size_t)row * ldb + (k0 - split));
    float4_ lo = *(const float4_*)s;
    float4_ hi = *(const float4_*)(s + 4);
    half8 r;
    r[0] = (_Float16)lo[0]; r[1] = (_Float16)lo[1];
    r[2] = (_Float16)lo[2]; r[3] = (_Float16)lo[3];
    r[4] = (_Float16)hi[0]; r[5] = (_Float16)hi[1];
    r[6] = (_Float16)hi[2]; r[7] = (_Float16)hi[3];
    return r;
}

// ---- coherence-point access primitives (NO fences, NO buffer_inv/wbl2) ----

// 16B coherent fragment load as two 8B agent-scope relaxed atomic loads (sc1:
// reads the coherence point directly; per-XCD L2 never holds stale copies).
__device__ __forceinline__ half8 ldg_coh16(const void* p) {
    union U { unsigned long long u; half4_t h; };
    U a, b;
    a.u = __hip_atomic_load((const unsigned long long*)p, __ATOMIC_RELAXED,
                            __HIP_MEMORY_SCOPE_AGENT);
    b.u = __hip_atomic_load((const unsigned long long*)p + 1, __ATOMIC_RELAXED,
                            __HIP_MEMORY_SCOPE_AGENT);
    half8 r;
#pragma unroll
    for (int i = 0; i < 4; ++i) { r[i] = a.h[i]; r[i + 4] = b.h[i]; }
    return r;
}

// 16B coalesced write-through store (full-line traffic at the coherence point).
__device__ __forceinline__ void stg_coh16(void* p, float4_ v) {
    asm volatile("global_store_dwordx4 %0, %1, off sc0 sc1" :: "v"(p), "v"(v) : "memory");
}

__device__ __forceinline__ void stg_coh_int(void* p, int v) {
    asm volatile("global_store_dword %0, %1, off sc0 sc1" :: "v"(p), "v"(v) : "memory");
}

// producer-side ordering: write-through stores acked (vmcnt 0), block barrier,
// then (thread 0) flag store. No cache maintenance involved.
__device__ __forceinline__ void publish(int* flag, int v) {
    asm volatile("s_waitcnt vmcnt(0)" ::: "memory");
    __syncthreads();
    if (threadIdx.x == 0) stg_coh_int(flag, v);
}

// ---- distributed flag waits (lane-parallel polling, no fences) ----

__device__ __forceinline__ void wave_wait64(const int* f, int target) {
    if (target <= 0) return;
    const int lane = threadIdx.x & 63;
    while (!__all(__hip_atomic_load(f + lane, __ATOMIC_RELAXED,
                                    __HIP_MEMORY_SCOPE_AGENT) >= target))
        __builtin_amdgcn_s_sleep(1);
}

__device__ __forceinline__ void wave_wait128(const int* f, int target) {
    if (target <= 0) return;
    const int lane = threadIdx.x & 63;
    for (;;) {
        int a = __hip_atomic_load(f + lane, __ATOMIC_RELAXED, __HIP_MEMORY_SCOPE_AGENT);
        int b = __hip_atomic_load(f + 64 + lane, __ATOMIC_RELAXED, __HIP_MEMORY_SCOPE_AGENT);
        if (__all((a >= target) && (b >= target))) break;
        __builtin_amdgcn_s_sleep(1);
    }
}

__device__ __forceinline__ void wave_wait8(const int* f, int target) {
    if (target <= 0) return;
    const int lane = threadIdx.x & 63;
    for (;;) {
        int v = __hip_atomic_load(f + (lane & 7), __ATOMIC_RELAXED, __HIP_MEMORY_SCOPE_AGENT);
        if (__all((lane >= 8) || (v >= target))) break;
        __builtin_amdgcn_s_sleep(1);
    }
}

// Convert input [128 b][512 t][64 i] fp32 -> fragment-major fp16 X[t][kt][quad][b][j]
extern "C" __global__ void prep_x(const float* __restrict__ in, char* __restrict__ ws) {
    const int t = blockIdx.x;
    char* X = ws + X_OFF + (size_t)t * X_TSTRIDE;
    for (int idx = threadIdx.x; idx < 8192; idx += 256) {
        int kt = idx >> 12, rem = idx & 4095;
        int quad = rem >> 10, rem2 = rem & 1023;
        int b = rem2 >> 3, j = rem2 & 7;
        int i = kt * 32 + quad * 8 + j;
        float v = in[(size_t)b * 32768 + (size_t)t * 64 + i];
        *(_Float16*)(X + (size_t)idx * 2) = (_Float16)v;
    }
}

extern "C" __global__ __launch_bounds__(256, 1)
void lstm_persistent(const float* __restrict__ Wih1, const float* __restrict__ Whh1,
                     const float* __restrict__ bih1, const float* __restrict__ bhh1,
                     const float* __restrict__ Wih2, const float* __restrict__ Whh2,
                     const float* __restrict__ bih2, const float* __restrict__ bhh2,
                     const float* __restrict__ Wout, const float* __restrict__ bout,
                     char* __restrict__ ws, float* __restrict__ out) {
    const int tid = threadIdx.x;
    const int w = tid >> 6, lane = tid & 63;
    const int quad = lane >> 4, cl = lane & 15;
    const int laneoff = quad * 2048 + cl * 16;
    int* fA = (int*)(ws + FLA_OFF);
    int* fB = (int*)(ws + FLB_OFF);
    int* fC = (int*)(ws + FLC_OFF);
    char* H1 = ws + H1_OFF;
    char* H2 = ws + H2_OFF;
    char* X  = ws + X_OFF;
    const int blk = blockIdx.x;
    // A: 32 KB 4-round redbuf + 4 KB transpose | B: 48 KB 1-round redbuf + 2 KB transpose
    __shared__ float4_ smem4[3200];   // 51200 B
    float*  redA  = (float*)smem4;
    char*   tbufA = (char*)smem4 + 32768;
    float4_* redB = smem4;
    char*   tbufB = (char*)smem4 + 49152;

    if (blk < NA) {
        // ---------- layer-1: h1 cols [c0,c0+16), K = 1088 (34 k-tiles), waves split K
        const int c0 = blk * 16;
        const int kbase = w * 9;
        half8 wfr[4][9];
#pragma unroll
        for (int nt = 0; nt < 4; ++nt) {
            int row = nt * 1024 + c0 + cl;
#pragma unroll
            for (int kk = 0; kk < 9; ++kk) {
                int ktg = kbase + kk;
                if (ktg < 34) wfr[nt][kk] = wfrag_load(Wih1, 64, Whh1, 1024, 64, row, ktg * 32 + quad * 8);
                else          wfr[nt][kk] = zero8();
            }
        }
        float ba[4];
#pragma unroll
        for (int g = 0; g < 4; ++g) ba[g] = bih1[g * 1024 + c0 + cl] + bhh1[g * 1024 + c0 + cl];
        float cst[2][4];
#pragma unroll
        for (int mi = 0; mi < 2; ++mi)
#pragma unroll
            for (int r = 0; r < 4; ++r) cst[mi][r] = 0.0f;
        const int cc = c0 + cl;
        const int tboffA = ((cc >> 3) & 1) * 2048 + (cc & 7) * 2;   // + m*16
        const int gbaseA = (c0 >> 5) * 8192 + ((c0 >> 4) & 1) * 4096;

        for (int t = 0; t < TSTEPS; ++t) {
            // deps: h1[t-1] ready (fA>=t); h1 phase free of B readers (fB>=t-1)
            if (w == 3) wave_wait128(fB, t - 1);
            wave_wait64(fA, t);

            const char* xb  = X + (size_t)t * X_TSTRIDE;
            const char* h1r = H1 + (((t & 1) ^ 1) ? H1_PHASE : 0);
            char*       h1w = H1 + ((t & 1) ? H1_PHASE : 0);
            const char* kb[9];
#pragma unroll
            for (int kk = 0; kk < 9; ++kk) {
                int ktg = kbase + kk; if (ktg > 33) ktg = 33;
                kb[kk] = (ktg < 2) ? (xb + ktg * 8192) : (h1r + (ktg - 2) * 8192);
            }
            float4_ acc[8][4];
#pragma unroll
            for (int mt = 0; mt < 8; ++mt)
#pragma unroll
                for (int nt = 0; nt < 4; ++nt) acc[mt][nt] = (float4_){0.f, 0.f, 0.f, 0.f};
            half8 af[2][9];
#pragma unroll
            for (int kk = 0; kk < 9; ++kk) af[0][kk] = ldg_coh16(kb[kk] + laneoff);
#pragma unroll
            for (int mt = 0; mt < 8; ++mt) {
                const int cur = mt & 1;
                if (mt < 7) {
#pragma unroll
                    for (int kk = 0; kk < 9; ++kk)
                        af[cur ^ 1][kk] = ldg_coh16(kb[kk] + laneoff + (mt + 1) * 256);
                }
#pragma unroll
                for (int kk = 0; kk < 9; ++kk)
#pragma unroll
                    for (int nt = 0; nt < 4; ++nt)
                        acc[mt][nt] = __builtin_amdgcn_mfma_f32_16x16x32_f16(
                            af[cur][kk], wfr[nt][kk], acc[mt][nt], 0, 0, 0);
            }
#pragma unroll
            for (int r = 0; r < 4; ++r) {
                if (w != r) {
#pragma unroll
                    for (int mi = 0; mi < 2; ++mi)
#pragma unroll
                        for (int nt = 0; nt < 4; ++nt)
                            *(float4_*)&redA[(((w * 2 + mi) * 4 + nt) * 64 + lane) * 4] = acc[2 * r + mi][nt];
                }
                __syncthreads();
                if (w == r) {
#pragma unroll
                    for (int wo = 0; wo < 4; ++wo) if (wo != r) {
#pragma unroll
                        for (int mi = 0; mi < 2; ++mi)
#pragma unroll
                            for (int nt = 0; nt < 4; ++nt)
                                acc[2 * r + mi][nt] += *(const float4_*)&redA[(((wo * 2 + mi) * 4 + nt) * 64 + lane) * 4];
                    }
                }
                __syncthreads();
            }
            float4_ mine[2][4];
#pragma unroll
            for (int r = 0; r < 4; ++r) if (w == r) {
#pragma unroll
                for (int mi = 0; mi < 2; ++mi)
#pragma unroll
                    for (int nt = 0; nt < 4; ++nt) mine[mi][nt] = acc[2 * r + mi][nt];
            }
            // epilogue -> LDS transpose buffer (2B each), then coalesced 16B stores
#pragma unroll
            for (int mi = 0; mi < 2; ++mi) {
#pragma unroll
                for (int r = 0; r < 4; ++r) {
                    float iv = mine[mi][0][r] + ba[0];
                    float fv = mine[mi][1][r] + ba[1];
                    float gv = mine[mi][2][r] + ba[2];
                    float ov = mine[mi][3][r] + ba[3];
                    float c = sigf(fv) * cst[mi][r] + sigf(iv) * tanhf(gv);
                    float h = sigf(ov) * tanhf(c);
                    cst[mi][r] = c;
                    int m = (2 * w + mi) * 16 + quad * 4 + r;
                    *(_Float16*)(tbufA + tboffA + m * 16) = (_Float16)h;
                }
            }
            __syncthreads();
            {
                float4_ v = *(const float4_*)(tbufA + tid * 16);
                stg_coh16(h1w + gbaseA + tid * 16, v);
            }
            publish(&fA[blk], t + 1);
        }
    } else if (blk < NA + NB) {
        // ---------- layer-2: h2 cols [c0,c0+8), K = 2048 (64 k-tiles), waves split K
        // waves 0-1 read h1[t] (wait on A); waves 2-3 read h2[t-1] (wait on B) -> overlap
        const int bb = blk - NA;
        const int c0 = bb * 8;
        const int kbase = w * 16;
        const int colB = c0 + (cl & 7);
        const int row0 = (cl < 8) ? colB : (1024 + colB);
        const int row1 = (cl < 8) ? (2048 + colB) : (3072 + colB);
        half8 wfr[2][16];
#pragma unroll
        for (int kk = 0; kk < 16; ++kk) {
            int k0 = (kbase + kk) * 32 + quad * 8;
            wfr[0][kk] = wfrag_load(Wih2, 1024, Whh2, 1024, 1024, row0, k0);
            wfr[1][kk] = wfrag_load(Wih2, 1024, Whh2, 1024, 1024, row1, k0);
        }
        const float bi = bih2[colB] + bhh2[colB];
        const float bf = bih2[1024 + colB] + bhh2[1024 + colB];
        const float bg = bih2[2048 + colB] + bhh2[2048 + colB];
        const float bo = bih2[3072 + colB] + bhh2[3072 + colB];
        float cst[2][4];
#pragma unroll
        for (int mi = 0; mi < 2; ++mi)
#pragma unroll
            for (int r = 0; r < 4; ++r) cst[mi][r] = 0.0f;
        const int tboffB = (colB & 7) * 2;                           // + m*16
        const int gbaseB = (c0 >> 5) * 8192 + ((c0 >> 3) & 3) * 2048;
        const bool lolane = (cl & 8) == 0;

        for (int t = 0; t < TSTEPS; ++t) {
            if (w < 2) {
                wave_wait64(fA, t + 1);            // h1[t] ready
            } else {
                if (w == 2) wave_wait8(fC, t - 1); // h2 phase free of C readers
                wave_wait128(fB, t);               // h2[t-1] ready
            }
            const char* h1c = H1 + ((t & 1) ? H1_PHASE : 0);
            const char* h2r = H2 + (((t & 1) ^ 1) ? H1_PHASE : 0);
            char*       h2w = H2 + ((t & 1) ? H1_PHASE : 0);
            const char* kb[16];
#pragma unroll
            for (int kk = 0; kk < 16; ++kk) {
                int ktg = kbase + kk;
                kb[kk] = (ktg < 32) ? (h1c + ktg * 8192) : (h2r + (ktg - 32) * 8192);
            }
            float4_ acc[8][2];
#pragma unroll
            for (int mt = 0; mt < 8; ++mt) {
                acc[mt][0] = (float4_){0.f, 0.f, 0.f, 0.f};
                acc[mt][1] = (float4_){0.f, 0.f, 0.f, 0.f};
            }
            // ktile-outer K-loop with depth-4 prefetch ring: slot kk&3 holds
            // all 8 batch-tile fragments of k-tile kk.
            half8 af[4][8];
#pragma unroll
            for (int p = 0; p < 4; ++p)
#pragma unroll
                for (int mt = 0; mt < 8; ++mt)
                    af[p][mt] = ldg_coh16(kb[p] + laneoff + mt * 256);
#pragma unroll
            for (int kk = 0; kk < 16; ++kk) {
                const int use = kk & 3;
#pragma unroll
                for (int mt = 0; mt < 8; ++mt) {
                    acc[mt][0] = __builtin_amdgcn_mfma_f32_16x16x32_f16(af[use][mt], wfr[0][kk], acc[mt][0], 0, 0, 0);
                    acc[mt][1] = __builtin_amdgcn_mfma_f32_16x16x32_f16(af[use][mt], wfr[1][kk], acc[mt][1], 0, 0, 0);
                }
                if (kk < 12) {
#pragma unroll
                    for (int mt = 0; mt < 8; ++mt)
                        af[use][mt] = ldg_coh16(kb[kk + 4] + laneoff + mt * 256);
                }
            }
            // single-round cross-wave reduction (2 syncthreads)
#pragma unroll
            for (int mt = 0; mt < 8; ++mt) {
                int ow = mt >> 1;
                if (ow != w) {
                    int s = mt - (mt > 2 * w + 1 ? 2 : 0);
#pragma unroll
                    for (int nt = 0; nt < 2; ++nt)
                        redB[((w * 6 + s) * 2 + nt) * 64 + lane] = acc[mt][nt];
                }
            }
            __syncthreads();
            float4_ mine[2][2];
#pragma unroll
            for (int mi = 0; mi < 2; ++mi) {
                int mt = 2 * w + mi;
#pragma unroll
                for (int nt = 0; nt < 2; ++nt) {
                    float4_ v = acc[mt][nt];
#pragma unroll
                    for (int wo = 0; wo < 4; ++wo) if (wo != w) {
                        int s = mt - (mt > 2 * wo + 1 ? 2 : 0);
                        v += redB[((wo * 6 + s) * 2 + nt) * 64 + lane];
                    }
                    mine[mi][nt] = v;
                }
            }
            // epilogue -> LDS transpose buffer, then coalesced 16B stores
#pragma unroll
            for (int mi = 0; mi < 2; ++mi) {
#pragma unroll
                for (int r = 0; r < 4; ++r) {
                    float d0 = mine[mi][0][r], d1 = mine[mi][1][r];
                    float s0 = __shfl_xor(d0, 8, 64);
                    float s1 = __shfl_xor(d1, 8, 64);
                    float iv = (lolane ? d0 : s0) + bi;
                    float fv = (lolane ? s0 : d0) + bf;
                    float gv = (lolane ? d1 : s1) + bg;
                    float ov = (lolane ? s1 : d1) + bo;
                    float c = sigf(fv) * cst[mi][r] + sigf(iv) * tanhf(gv);
                    float h = sigf(ov) * tanhf(c);
                    cst[mi][r] = c;
                    if (lolane) {
                        int m = (2 * w + mi) * 16 + quad * 4 + r;
                        *(_Float16*)(tbufB + tboffB + m * 16) = (_Float16)h;
                    }
                }
            }
            __syncthreads();
            if (tid < 128) {
                float4_ v = *(const float4_*)(tbufB + tid * 16);
                stg_coh16(h2w + gbaseB + tid * 16, v);
            }
            publish(&fB[bb], t + 1);
        }
    } else {
        // ---------- output: batch tile cb, y = h2 @ Wout^T + bout, K = 1024
        const int cb = blk - NA - NB;
        const int kbase = w * 8;
        half8 wfr[4][8];
#pragma unroll
        for (int nt = 0; nt < 4; ++nt) {
            int row = nt * 16 + cl;
#pragma unroll
            for (int kk = 0; kk < 8; ++kk)
                wfr[nt][kk] = wfrag_load(Wout, 1024, Wout, 1024, 1 << 30, row, (kbase + kk) * 32 + quad * 8);
        }
        const float bo_ = bout[w * 16 + cl];
        float* redC = (float*)smem4;

        for (int t = 0; t < TSTEPS; ++t) {
            wave_wait128(fB, t + 1);   // h2[t] ready
            const char* h2c = H2 + ((t & 1) ? H1_PHASE : 0);
            float4_ acc[4];
#pragma unroll
            for (int nt = 0; nt < 4; ++nt) acc[nt] = (float4_){0.f, 0.f, 0.f, 0.f};
            half8 af[8];
#pragma unroll
            for (int kk = 0; kk < 8; ++kk)
                af[kk] = ldg_coh16(h2c + (kbase + kk) * 8192 + laneoff + cb * 256);
#pragma unroll
            for (int kk = 0; kk < 8; ++kk)
#pragma unroll
                for (int nt = 0; nt < 4; ++nt)
                    acc[nt] = __builtin_amdgcn_mfma_f32_16x16x32_f16(af[kk], wfr[nt][kk], acc[nt], 0, 0, 0);
#pragma unroll
            for (int r = 0; r < 4; ++r) {
                if (w != r) *(float4_*)&redC[(w * 64 + lane) * 4] = acc[r];
                __syncthreads();
                if (w == r) {
#pragma unroll
                    for (int wo = 0; wo < 4; ++wo) if (wo != r)
                        acc[r] += *(const float4_*)&redC[(wo * 64 + lane) * 4];
                }
                __syncthreads();
            }
            float4_ myy = acc[0];
#pragma unroll
            for (int r = 1; r < 4; ++r) if (w == r) myy = acc[r];
#pragma unroll
            for (int r = 0; r < 4; ++r) {
                int m = cb * 16 + quad * 4 + r;
                out[(size_t)m * 32768 + (size_t)t * 64 + (w * 16 + cl)] = myy[r] + bo_;
            }
            publish(&fC[cb], t + 1);
        }
    }
}

extern "C" void kernel_launch(void* const* d_in, const int* in_sizes, int n_in,
                              void* d_out, int out_size, void* d_ws, size_t ws_size,
                              hipStream_t stream) {
    const float* inp  = (const float*)d_in[0];
    const float* Wih1 = (const float*)d_in[1];
    const float* Whh1 = (const float*)d_in[2];
    const float* bih1 = (const float*)d_in[3];
    const float* bhh1 = (const float*)d_in[4];
    const float* Wih2 = (const float*)d_in[5];
    const float* Whh2 = (const float*)d_in[6];
    const float* bih2 = (const float*)d_in[7];
    const float* bhh2 = (const float*)d_in[8];
    const float* Wout = (const float*)d_in[9];
    const float* bout = (const float*)d_in[10];
    char* ws = (char*)d_ws;

    hipMemsetAsync(d_ws, 0, ZERO_BYTES, stream);
    prep_x<<<TSTEPS, 256, 0, stream>>>(inp, ws);
    lstm_persistent<<<NA + NB + NC, 256, 0, stream>>>(Wih1, Whh1, bih1, bhh1,
                                                      Wih2, Whh2, bih2, bhh2,
                                                      Wout, bout, ws, (float*)d_out);
}

// Round 5
// 12468.269 us; speedup vs baseline: 1.7616x; 1.7616x over previous
//
#include <hip/hip_runtime.h>
#include <hip/hip_fp16.h>

typedef _Float16 half8 __attribute__((ext_vector_type(8)));
typedef _Float16 half4_t __attribute__((ext_vector_type(4)));
typedef float    float4_ __attribute__((ext_vector_type(4)));

#define TSTEPS 512
#define NA 64
#define NB 128
#define NC 8
#define FSTRIDE 32                // ints per flag slot = 128 B (own cache line)

// workspace layout (bytes)
#define FLA_OFF   0               // 64 flags  x 128 B
#define FLB_OFF   8192            // 128 flags x 128 B
#define FLC_OFF   24576           // 8 flags   x 128 B
#define H1_OFF    32768
#define H1_PHASE  262144          // 1024 cols x 128 batch x 2B, fragment-major
#define H2_OFF    (H1_OFF + 2 * H1_PHASE)
#define X_OFF     (H2_OFF + 2 * H1_PHASE)
#define X_TSTRIDE 16384           // 64 cols x 128 batch x 2B per step
#define ZERO_BYTES X_OFF          // flags + H1 + H2 zeroed each call

__device__ __forceinline__ float sigf(float x) { return 1.0f / (1.0f + __expf(-x)); }

__device__ __forceinline__ half8 zero8() {
    half8 z;
#pragma unroll
    for (int j = 0; j < 8; ++j) z[j] = (_Float16)0.0f;
    return z;
}

__device__ __forceinline__ half8 wfrag_load(const float* Wa, int lda,
                                            const float* Wb, int ldb,
                                            int split, int row, int k0) {
    const float* s = (k0 < split) ? (Wa + (size_t)row * lda + k0)
                                  : (Wb + (size_t)row * ldb + (k0 - split));
    float4_ lo = *(const float4_*)s;
    float4_ hi = *(const float4_*)(s + 4);
    half8 r;
    r[0] = (_Float16)lo[0]; r[1] = (_Float16)lo[1];
    r[2] = (_Float16)lo[2]; r[3] = (_Float16)lo[3];
    r[4] = (_Float16)hi[0]; r[5] = (_Float16)hi[1];
    r[6] = (_Float16)hi[2]; r[7] = (_Float16)hi[3];
    return r;
}

// ---- coherence-point access primitives (NO fences, NO buffer_inv/wbl2) ----

// 16B coherent fragment load as two 8B agent-scope relaxed atomic loads (sc1:
// reads the coherence point directly; per-XCD L2 never holds stale copies).
__device__ __forceinline__ half8 ldg_coh16(const void* p) {
    union U { unsigned long long u; half4_t h; };
    U a, b;
    a.u = __hip_atomic_load((const unsigned long long*)p, __ATOMIC_RELAXED,
                            __HIP_MEMORY_SCOPE_AGENT);
    b.u = __hip_atomic_load((const unsigned long long*)p + 1, __ATOMIC_RELAXED,
                            __HIP_MEMORY_SCOPE_AGENT);
    half8 r;
#pragma unroll
    for (int i = 0; i < 4; ++i) { r[i] = a.h[i]; r[i + 4] = b.h[i]; }
    return r;
}

// 2B write-through store (sc0 sc1): lands at the coherence point, acked by vmcnt.
__device__ __forceinline__ void stg_coh_h(void* p, float v) {
    union { _Float16 h; unsigned short s; } u;
    u.h = (_Float16)v;
    unsigned int d = u.s;
    asm volatile("global_store_short %0, %1, off sc0 sc1" :: "v"(p), "v"(d) : "memory");
}

__device__ __forceinline__ void stg_coh_int(void* p, int v) {
    asm volatile("global_store_dword %0, %1, off sc0 sc1" :: "v"(p), "v"(v) : "memory");
}

// producer-side ordering: my write-through stores acked (vmcnt 0), then block
// barrier, then (thread 0) flag store. No cache maintenance involved.
__device__ __forceinline__ void publish(int* fbase, int idx, int v) {
    asm volatile("s_waitcnt vmcnt(0)" ::: "memory");
    __syncthreads();
    if (threadIdx.x == 0) stg_coh_int(fbase + idx * FSTRIDE, v);
}

// ---- de-contended flag waits: flags on private lines, ONE polling wave ----

__device__ __forceinline__ int ld_flag(const int* f, int idx) {
    return __hip_atomic_load(f + idx * FSTRIDE, __ATOMIC_RELAXED,
                             __HIP_MEMORY_SCOPE_AGENT);
}

// A-group: need all fA >= t (h1[t-1] ready) and all fB >= t-1 (phase free)
__device__ __forceinline__ void waitA(const int* fA, const int* fB, int t) {
    if (threadIdx.x < 64) {
        const int lane = threadIdx.x;
        for (;;) {
            int a  = ld_flag(fA, lane);
            int b0 = ld_flag(fB, lane);
            int b1 = ld_flag(fB, 64 + lane);
            if (__all((a >= t) && (b0 >= t - 1) && (b1 >= t - 1))) break;
            __builtin_amdgcn_s_sleep(1);
        }
    }
    __syncthreads();
}

// B-group: fA >= t+1 (h1[t]), fB >= t (h2[t-1]), fC >= t-1 (phase free)
__device__ __forceinline__ void waitB(const int* fA, const int* fB, const int* fC, int t) {
    if (threadIdx.x < 64) {
        const int lane = threadIdx.x;
        for (;;) {
            int a  = ld_flag(fA, lane);
            int b0 = ld_flag(fB, lane);
            int b1 = ld_flag(fB, 64 + lane);
            int c  = ld_flag(fC, lane & 7);
            if (__all((a >= t + 1) && (b0 >= t) && (b1 >= t) && (c >= t - 1))) break;
            __builtin_amdgcn_s_sleep(1);
        }
    }
    __syncthreads();
}

// C-group: fB >= t+1 (h2[t] ready)
__device__ __forceinline__ void waitC(const int* fB, int t) {
    if (threadIdx.x < 64) {
        const int lane = threadIdx.x;
        for (;;) {
            int b0 = ld_flag(fB, lane);
            int b1 = ld_flag(fB, 64 + lane);
            if (__all((b0 >= t + 1) && (b1 >= t + 1))) break;
            __builtin_amdgcn_s_sleep(1);
        }
    }
    __syncthreads();
}

// Convert input [128 b][512 t][64 i] fp32 -> fragment-major fp16 X[t][kt][quad][b][j]
extern "C" __global__ void prep_x(const float* __restrict__ in, char* __restrict__ ws) {
    const int t = blockIdx.x;
    char* X = ws + X_OFF + (size_t)t * X_TSTRIDE;
    for (int idx = threadIdx.x; idx < 8192; idx += 256) {
        int kt = idx >> 12, rem = idx & 4095;
        int quad = rem >> 10, rem2 = rem & 1023;
        int b = rem2 >> 3, j = rem2 & 7;
        int i = kt * 32 + quad * 8 + j;
        float v = in[(size_t)b * 32768 + (size_t)t * 64 + i];
        *(_Float16*)(X + (size_t)idx * 2) = (_Float16)v;
    }
}

extern "C" __global__ __launch_bounds__(256, 1)
void lstm_persistent(const float* __restrict__ Wih1, const float* __restrict__ Whh1,
                     const float* __restrict__ bih1, const float* __restrict__ bhh1,
                     const float* __restrict__ Wih2, const float* __restrict__ Whh2,
                     const float* __restrict__ bih2, const float* __restrict__ bhh2,
                     const float* __restrict__ Wout, const float* __restrict__ bout,
                     char* __restrict__ ws, float* __restrict__ out) {
    const int tid = threadIdx.x;
    const int w = tid >> 6, lane = tid & 63;
    const int quad = lane >> 4, cl = lane & 15;
    const int laneoff = quad * 2048 + cl * 16;
    int* fA = (int*)(ws + FLA_OFF);
    int* fB = (int*)(ws + FLB_OFF);
    int* fC = (int*)(ws + FLC_OFF);
    char* H1 = ws + H1_OFF;
    char* H2 = ws + H2_OFF;
    char* X  = ws + X_OFF;
    const int blk = blockIdx.x;
    __shared__ float redbuf[8192];

    if (blk < NA) {
        // ---------- layer-1: h1 cols [c0,c0+16), K = 1088 (34 k-tiles), waves split K
        const int c0 = blk * 16;
        const int kbase = w * 9;
        half8 wfr[4][9];
#pragma unroll
        for (int nt = 0; nt < 4; ++nt) {
            int row = nt * 1024 + c0 + cl;
#pragma unroll
            for (int kk = 0; kk < 9; ++kk) {
                int ktg = kbase + kk;
                if (ktg < 34) wfr[nt][kk] = wfrag_load(Wih1, 64, Whh1, 1024, 64, row, ktg * 32 + quad * 8);
                else          wfr[nt][kk] = zero8();
            }
        }
        float ba[4];
#pragma unroll
        for (int g = 0; g < 4; ++g) ba[g] = bih1[g * 1024 + c0 + cl] + bhh1[g * 1024 + c0 + cl];
        float cst[2][4];
#pragma unroll
        for (int mi = 0; mi < 2; ++mi)
#pragma unroll
            for (int r = 0; r < 4; ++r) cst[mi][r] = 0.0f;
        const int cc = c0 + cl;
        const int woffbase = (cc >> 5) * 8192 + ((cc >> 3) & 3) * 2048 + (cc & 7) * 2;

        for (int t = 0; t < TSTEPS; ++t) {
            waitA(fA, fB, t);

            const char* xb  = X + (size_t)t * X_TSTRIDE;
            const char* h1r = H1 + (((t & 1) ^ 1) ? H1_PHASE : 0);
            char*       h1w = H1 + ((t & 1) ? H1_PHASE : 0);
            const char* kb[9];
#pragma unroll
            for (int kk = 0; kk < 9; ++kk) {
                int ktg = kbase + kk; if (ktg > 33) ktg = 33;
                kb[kk] = (ktg < 2) ? (xb + ktg * 8192) : (h1r + (ktg - 2) * 8192);
            }
            float4_ acc[8][4];
#pragma unroll
            for (int mt = 0; mt < 8; ++mt)
#pragma unroll
                for (int nt = 0; nt < 4; ++nt) acc[mt][nt] = (float4_){0.f, 0.f, 0.f, 0.f};
            half8 af[2][9];
#pragma unroll
            for (int kk = 0; kk < 9; ++kk) af[0][kk] = ldg_coh16(kb[kk] + laneoff);
#pragma unroll
            for (int mt = 0; mt < 8; ++mt) {
                const int cur = mt & 1;
                if (mt < 7) {
#pragma unroll
                    for (int kk = 0; kk < 9; ++kk)
                        af[cur ^ 1][kk] = ldg_coh16(kb[kk] + laneoff + (mt + 1) * 256);
                }
#pragma unroll
                for (int kk = 0; kk < 9; ++kk)
#pragma unroll
                    for (int nt = 0; nt < 4; ++nt)
                        acc[mt][nt] = __builtin_amdgcn_mfma_f32_16x16x32_f16(
                            af[cur][kk], wfr[nt][kk], acc[mt][nt], 0, 0, 0);
            }
#pragma unroll
            for (int r = 0; r < 4; ++r) {
                if (w != r) {
#pragma unroll
                    for (int mi = 0; mi < 2; ++mi)
#pragma unroll
                        for (int nt = 0; nt < 4; ++nt)
                            *(float4_*)&redbuf[(((w * 2 + mi) * 4 + nt) * 64 + lane) * 4] = acc[2 * r + mi][nt];
                }
                __syncthreads();
                if (w == r) {
#pragma unroll
                    for (int wo = 0; wo < 4; ++wo) if (wo != r) {
#pragma unroll
                        for (int mi = 0; mi < 2; ++mi)
#pragma unroll
                            for (int nt = 0; nt < 4; ++nt)
                                acc[2 * r + mi][nt] += *(const float4_*)&redbuf[(((wo * 2 + mi) * 4 + nt) * 64 + lane) * 4];
                    }
                }
                __syncthreads();
            }
            float4_ mine[2][4];
#pragma unroll
            for (int r = 0; r < 4; ++r) if (w == r) {
#pragma unroll
                for (int mi = 0; mi < 2; ++mi)
#pragma unroll
                    for (int nt = 0; nt < 4; ++nt) mine[mi][nt] = acc[2 * r + mi][nt];
            }
#pragma unroll
            for (int mi = 0; mi < 2; ++mi) {
#pragma unroll
                for (int r = 0; r < 4; ++r) {
                    float iv = mine[mi][0][r] + ba[0];
                    float fv = mine[mi][1][r] + ba[1];
                    float gv = mine[mi][2][r] + ba[2];
                    float ov = mine[mi][3][r] + ba[3];
                    float c = sigf(fv) * cst[mi][r] + sigf(iv) * tanhf(gv);
                    float h = sigf(ov) * tanhf(c);
                    cst[mi][r] = c;
                    int m = (2 * w + mi) * 16 + quad * 4 + r;
                    stg_coh_h(h1w + woffbase + m * 16, h);
                }
            }
            publish(fA, blk, t + 1);
        }
    } else if (blk < NA + NB) {
        // ---------- layer-2: h2 cols [c0,c0+8), K = 2048 (64 k-tiles), waves split K
        const int bb = blk - NA;
        const int c0 = bb * 8;
        const int kbase = w * 16;
        const int colB = c0 + (cl & 7);
        const int row0 = (cl < 8) ? colB : (1024 + colB);
        const int row1 = (cl < 8) ? (2048 + colB) : (3072 + colB);
        half8 wfr[2][16];
#pragma unroll
        for (int kk = 0; kk < 16; ++kk) {
            int k0 = (kbase + kk) * 32 + quad * 8;
            wfr[0][kk] = wfrag_load(Wih2, 1024, Whh2, 1024, 1024, row0, k0);
            wfr[1][kk] = wfrag_load(Wih2, 1024, Whh2, 1024, 1024, row1, k0);
        }
        const float bi = bih2[colB] + bhh2[colB];
        const float bf = bih2[1024 + colB] + bhh2[1024 + colB];
        const float bg = bih2[2048 + colB] + bhh2[2048 + colB];
        const float bo = bih2[3072 + colB] + bhh2[3072 + colB];
        float cst[2][4];
#pragma unroll
        for (int mi = 0; mi < 2; ++mi)
#pragma unroll
            for (int r = 0; r < 4; ++r) cst[mi][r] = 0.0f;
        const int woffbase = (c0 >> 5) * 8192 + ((c0 >> 3) & 3) * 2048 + (cl & 7) * 2;
        const bool lolane = (cl & 8) == 0;

        for (int t = 0; t < TSTEPS; ++t) {
            waitB(fA, fB, fC, t);

            const char* h1c = H1 + ((t & 1) ? H1_PHASE : 0);
            const char* h2r = H2 + (((t & 1) ^ 1) ? H1_PHASE : 0);
            char*       h2w = H2 + ((t & 1) ? H1_PHASE : 0);
            const char* kb[16];
#pragma unroll
            for (int kk = 0; kk < 16; ++kk) {
                int ktg = kbase + kk;
                kb[kk] = (ktg < 32) ? (h1c + ktg * 8192) : (h2r + (ktg - 32) * 8192);
            }
            float4_ acc[8][2];
#pragma unroll
            for (int mt = 0; mt < 8; ++mt) {
                acc[mt][0] = (float4_){0.f, 0.f, 0.f, 0.f};
                acc[mt][1] = (float4_){0.f, 0.f, 0.f, 0.f};
            }
            half8 af[2][16];
#pragma unroll
            for (int kk = 0; kk < 16; ++kk) af[0][kk] = ldg_coh16(kb[kk] + laneoff);
#pragma unroll
            for (int mt = 0; mt < 8; ++mt) {
                const int cur = mt & 1;
                if (mt < 7) {
#pragma unroll
                    for (int kk = 0; kk < 16; ++kk)
                        af[cur ^ 1][kk] = ldg_coh16(kb[kk] + laneoff + (mt + 1) * 256);
                }
#pragma unroll
                for (int kk = 0; kk < 16; ++kk) {
                    acc[mt][0] = __builtin_amdgcn_mfma_f32_16x16x32_f16(af[cur][kk], wfr[0][kk], acc[mt][0], 0, 0, 0);
                    acc[mt][1] = __builtin_amdgcn_mfma_f32_16x16x32_f16(af[cur][kk], wfr[1][kk], acc[mt][1], 0, 0, 0);
                }
            }
#pragma unroll
            for (int r = 0; r < 4; ++r) {
                if (w != r) {
#pragma unroll
                    for (int mi = 0; mi < 2; ++mi)
#pragma unroll
                        for (int nt = 0; nt < 2; ++nt)
                            *(float4_*)&redbuf[(((w * 2 + mi) * 2 + nt) * 64 + lane) * 4] = acc[2 * r + mi][nt];
                }
                __syncthreads();
                if (w == r) {
#pragma unroll
                    for (int wo = 0; wo < 4; ++wo) if (wo != r) {
#pragma unroll
                        for (int mi = 0; mi < 2; ++mi)
#pragma unroll
                            for (int nt = 0; nt < 2; ++nt)
                                acc[2 * r + mi][nt] += *(const float4_*)&redbuf[(((wo * 2 + mi) * 2 + nt) * 64 + lane) * 4];
                    }
                }
                __syncthreads();
            }
            float4_ mine[2][2];
#pragma unroll
            for (int r = 0; r < 4; ++r) if (w == r) {
#pragma unroll
                for (int mi = 0; mi < 2; ++mi) {
                    mine[mi][0] = acc[2 * r + mi][0];
                    mine[mi][1] = acc[2 * r + mi][1];
                }
            }
#pragma unroll
            for (int mi = 0; mi < 2; ++mi) {
#pragma unroll
                for (int r = 0; r < 4; ++r) {
                    float d0 = mine[mi][0][r], d1 = mine[mi][1][r];
                    float s0 = __shfl_xor(d0, 8, 64);
                    float s1 = __shfl_xor(d1, 8, 64);
                    float iv = (lolane ? d0 : s0) + bi;
                    float fv = (lolane ? s0 : d0) + bf;
                    float gv = (lolane ? d1 : s1) + bg;
                    float ov = (lolane ? s1 : d1) + bo;
                    float c = sigf(fv) * cst[mi][r] + sigf(iv) * tanhf(gv);
                    float h = sigf(ov) * tanhf(c);
                    cst[mi][r] = c;
                    if (lolane) {
                        int m = (2 * w + mi) * 16 + quad * 4 + r;
                        stg_coh_h(h2w + woffbase + m * 16, h);
                    }
                }
            }
            publish(fB, bb, t + 1);
        }
    } else {
        // ---------- output: batch tile cb, y = h2 @ Wout^T + bout, K = 1024
        const int cb = blk - NA - NB;
        const int kbase = w * 8;
        half8 wfr[4][8];
#pragma unroll
        for (int nt = 0; nt < 4; ++nt) {
            int row = nt * 16 + cl;
#pragma unroll
            for (int kk = 0; kk < 8; ++kk)
                wfr[nt][kk] = wfrag_load(Wout, 1024, Wout, 1024, 1 << 30, row, (kbase + kk) * 32 + quad * 8);
        }
        const float bo_ = bout[w * 16 + cl];

        for (int t = 0; t < TSTEPS; ++t) {
            waitC(fB, t);
            const char* h2c = H2 + ((t & 1) ? H1_PHASE : 0);
            float4_ acc[4];
#pragma unroll
            for (int nt = 0; nt < 4; ++nt) acc[nt] = (float4_){0.f, 0.f, 0.f, 0.f};
            half8 af[8];
#pragma unroll
            for (int kk = 0; kk < 8; ++kk)
                af[kk] = ldg_coh16(h2c + (kbase + kk) * 8192 + laneoff + cb * 256);
#pragma unroll
            for (int kk = 0; kk < 8; ++kk)
#pragma unroll
                for (int nt = 0; nt < 4; ++nt)
                    acc[nt] = __builtin_amdgcn_mfma_f32_16x16x32_f16(af[kk], wfr[nt][kk], acc[nt], 0, 0, 0);
#pragma unroll
            for (int r = 0; r < 4; ++r) {
                if (w != r) *(float4_*)&redbuf[(w * 64 + lane) * 4] = acc[r];
                __syncthreads();
                if (w == r) {
#pragma unroll
                    for (int wo = 0; wo < 4; ++wo) if (wo != r)
                        acc[r] += *(const float4_*)&redbuf[(wo * 64 + lane) * 4];
                }
                __syncthreads();
            }
            float4_ myy = acc[0];
#pragma unroll
            for (int r = 1; r < 4; ++r) if (w == r) myy = acc[r];
#pragma unroll
            for (int r = 0; r < 4; ++r) {
                int m = cb * 16 + quad * 4 + r;
                out[(size_t)m * 32768 + (size_t)t * 64 + (w * 16 + cl)] = myy[r] + bo_;
            }
            publish(fC, cb, t + 1);
        }
    }
}

extern "C" void kernel_launch(void* const* d_in, const int* in_sizes, int n_in,
                              void* d_out, int out_size, void* d_ws, size_t ws_size,
                              hipStream_t stream) {
    const float* inp  = (const float*)d_in[0];
    const float* Wih1 = (const float*)d_in[1];
    const float* Whh1 = (const float*)d_in[2];
    const float* bih1 = (const float*)d_in[3];
    const float* bhh1 = (const float*)d_in[4];
    const float* Wih2 = (const float*)d_in[5];
    const float* Whh2 = (const float*)d_in[6];
    const float* bih2 = (const float*)d_in[7];
    const float* bhh2 = (const float*)d_in[8];
    const float* Wout = (const float*)d_in[9];
    const float* bout = (const float*)d_in[10];
    char* ws = (char*)d_ws;

    hipMemsetAsync(d_ws, 0, ZERO_BYTES, stream);
    prep_x<<<TSTEPS, 256, 0, stream>>>(inp, ws);
    lstm_persistent<<<NA + NB + NC, 256, 0, stream>>>(Wih1, Whh1, bih1, bhh1,
                                                      Wih2, Whh2, bih2, bhh2,
                                                      Wout, bout, ws, (float*)d_out);
}